// Round 1
// baseline (879.446 us; speedup 1.0000x reference)
//
#include <hip/hip_runtime.h>
#include <math.h>

#define NB 8
#define NC 128
#define NPOS 2000
#define NKCOLS 32000
#define IN_EPS 1e-3f
#define BN_EPS 1e-5f

// workspace layout (float offsets)
#define WS_SUM   0
#define WS_SQ    1024
#define WS_MU    2048
#define WS_SCALE 3072
#define WS_W0T   4096
#define WS_WQT   20480
#define WS_WKT   36864
#define WS_WVT   53248

// ---------------- K0: transpose weights [o][c] -> [c][o] ----------------
__global__ __launch_bounds__(256) void k_transpose(const float* __restrict__ w0,
    const float* __restrict__ wq, const float* __restrict__ wk,
    const float* __restrict__ wv, float* __restrict__ ws) {
  int idx = blockIdx.x * 256 + threadIdx.x;   // 0..65535
  int m = idx >> 14;
  int o = (idx >> 7) & 127;
  int c = idx & 127;
  const float* src = (m == 0) ? w0 : (m == 1) ? wq : (m == 2) ? wk : wv;
  float* dst = ws + WS_W0T + m * 16384;
  dst[c * 128 + o] = src[o * 128 + c];
}

// 8x8 register-tiled GEMM: dst[r][j] = sum_kk wT[kk][r0+r] * xs[kk][c0+j]
__device__ __forceinline__ void gemm_tile(const float* __restrict__ wT,
                                          const float (*xs)[128],
                                          int r0, int c0, float (&dst)[8][8]) {
#pragma unroll
  for (int r = 0; r < 8; ++r)
#pragma unroll
    for (int j = 0; j < 8; ++j) dst[r][j] = 0.f;
#pragma unroll 2
  for (int kk = 0; kk < 128; ++kk) {
    float a[8], bb[8];
    const float4* wr = (const float4*)(wT + kk * 128 + r0);
    ((float4*)a)[0] = wr[0];
    ((float4*)a)[1] = wr[1];
    const float4* br = (const float4*)(&xs[kk][c0]);
    ((float4*)bb)[0] = br[0];
    ((float4*)bb)[1] = br[1];
#pragma unroll
    for (int r = 0; r < 8; ++r)
#pragma unroll
      for (int j = 0; j < 8; ++j)
        dst[r][j] = fmaf(a[r], bb[j], dst[r][j]);
  }
}

// ---------------- K1: conv stats (sum, sumsq of h per (b,c)) ----------------
__global__ __launch_bounds__(256) void k_stats(const float* __restrict__ x,
    const float* __restrict__ w0T, const float* __restrict__ b0,
    float* __restrict__ sum, float* __restrict__ sumsq) {
  __shared__ float xs[128][128];
  const int b = blockIdx.y;
  const int col0 = blockIdx.x * 128;
  const float* xb = x + (size_t)b * NC * NKCOLS + col0;
  const int tid = threadIdx.x;
  for (int i = tid; i < 128 * 32; i += 256) {
    int r = i >> 5, jj = (i & 31) << 2;
    *(float4*)(&xs[r][jj]) = *(const float4*)(xb + (size_t)r * NKCOLS + jj);
  }
  __syncthreads();
  const int ty = tid >> 4, tx = tid & 15;
  const int r0 = ty * 8, c0 = tx * 8;
  float acc[8][8];
  gemm_tile(w0T, xs, r0, c0, acc);
  float bias[8];
  ((float4*)bias)[0] = *(const float4*)(b0 + r0);
  ((float4*)bias)[1] = *(const float4*)(b0 + r0 + 4);
  float s[8], sq[8];
#pragma unroll
  for (int r = 0; r < 8; ++r) {
    s[r] = 0.f; sq[r] = 0.f;
#pragma unroll
    for (int j = 0; j < 8; ++j) {
      float h = acc[r][j] + bias[r];
      s[r] += h;
      sq[r] += h * h;
    }
  }
#pragma unroll
  for (int r = 0; r < 8; ++r) {
    s[r] += __shfl_xor(s[r], 8, 16);
    sq[r] += __shfl_xor(sq[r], 8, 16);
    s[r] += __shfl_xor(s[r], 4, 16);
    sq[r] += __shfl_xor(sq[r], 4, 16);
    s[r] += __shfl_xor(s[r], 2, 16);
    sq[r] += __shfl_xor(sq[r], 2, 16);
    s[r] += __shfl_xor(s[r], 1, 16);
    sq[r] += __shfl_xor(sq[r], 1, 16);
  }
  if (tx == 0) {
#pragma unroll
    for (int r = 0; r < 8; ++r) {
      atomicAdd(&sum[b * 128 + r0 + r], s[r]);
      atomicAdd(&sumsq[b * 128 + r0 + r], sq[r]);
    }
  }
}

// ---------------- K2: fold IN + BN into scale/shift ----------------
// IN-normalized h has zero mean per (b,c)  =>  BN mean == 0 exactly,
// BN var[c] = mean_b( var_bc / (var_bc + IN_EPS) ).
__global__ void k_fold(const float* __restrict__ ws_in, const float* __restrict__ bn_g,
                       float* __restrict__ mu_out, float* __restrict__ sc_out) {
  int c = threadIdx.x;  // 128 threads
  const float* sum = ws_in + WS_SUM;
  const float* sq = ws_in + WS_SQ;
  float var[NB], muv[NB];
  float bvar = 0.f;
#pragma unroll
  for (int b = 0; b < NB; ++b) {
    float m = sum[b * 128 + c] * (1.f / NKCOLS);
    float v = sq[b * 128 + c] * (1.f / NKCOLS) - m * m;
    muv[b] = m;
    var[b] = v;
    bvar += v / (v + IN_EPS);
  }
  bvar *= 0.125f;
  float s2 = rsqrtf(bvar + BN_EPS);
  float g = bn_g[c];
#pragma unroll
  for (int b = 0; b < NB; ++b) {
    mu_out[b * 128 + c] = muv[b];
    sc_out[b * 128 + c] = rsqrtf(var[b] + IN_EPS) * s2 * g;
  }
}

// ---------------- K3: fused conv+norm+qkv+softmax+agg ----------------
__global__ __launch_bounds__(256) void k_fused(const float* __restrict__ x,
    const float* __restrict__ x_row, const float* __restrict__ ws,
    const float* __restrict__ b0, const float* __restrict__ bn_b,
    const float* __restrict__ bq, const float* __restrict__ bk,
    const float* __restrict__ bv, const float* __restrict__ gamma1,
    float* __restrict__ out) {
  __shared__ float xs[128][128];
  const int b = blockIdx.y;
  const int ct = blockIdx.x;
  const int col0 = ct * 128;
  const float* xb = x + (size_t)b * NC * NKCOLS + col0;
  const int tid = threadIdx.x;
  for (int i = tid; i < 128 * 32; i += 256) {
    int r = i >> 5, jj = (i & 31) << 2;
    *(float4*)(&xs[r][jj]) = *(const float4*)(xb + (size_t)r * NKCOLS + jj);
  }
  __syncthreads();
  const int ty = tid >> 4, tx = tid & 15;
  const int r0 = ty * 8, c0 = tx * 8;

  // h = w0 @ x
  float acc[8][8];
  gemm_tile(ws + WS_W0T, xs, r0, c0, acc);

  // normalize + relu -> back into xs
  float muv[8], sc[8], shv[8], b0v[8];
  {
    const float* mu = ws + WS_MU + b * 128;
    const float* scl = ws + WS_SCALE + b * 128;
    ((float4*)muv)[0] = *(const float4*)(mu + r0);
    ((float4*)muv)[1] = *(const float4*)(mu + r0 + 4);
    ((float4*)sc)[0] = *(const float4*)(scl + r0);
    ((float4*)sc)[1] = *(const float4*)(scl + r0 + 4);
    ((float4*)shv)[0] = *(const float4*)(bn_b + r0);
    ((float4*)shv)[1] = *(const float4*)(bn_b + r0 + 4);
    ((float4*)b0v)[0] = *(const float4*)(b0 + r0);
    ((float4*)b0v)[1] = *(const float4*)(b0 + r0 + 4);
  }
  __syncthreads();  // all reads of x tile done
#pragma unroll
  for (int r = 0; r < 8; ++r) {
#pragma unroll
    for (int j = 0; j < 8; ++j) {
      float h = acc[r][j] + b0v[r];
      h = (h - muv[r]) * sc[r] + shv[r];
      xs[r0 + r][c0 + j] = fmaxf(h, 0.f);
    }
  }
  __syncthreads();

  // q and k
  float qv[8][8];
  gemm_tile(ws + WS_WQT, xs, r0, c0, qv);
  gemm_tile(ws + WS_WKT, xs, r0, c0, acc);
  float bqv[8], bkv[8], bvv[8];
  ((float4*)bqv)[0] = *(const float4*)(bq + r0);
  ((float4*)bqv)[1] = *(const float4*)(bq + r0 + 4);
  ((float4*)bkv)[0] = *(const float4*)(bk + r0);
  ((float4*)bkv)[1] = *(const float4*)(bk + r0 + 4);
  ((float4*)bvv)[0] = *(const float4*)(bv + r0);
  ((float4*)bvv)[1] = *(const float4*)(bv + r0 + 4);

  // softmax over K=16 neighbors: 8 cols here + 8 cols in partner lane (lane^1)
  float sden[8];
#pragma unroll
  for (int r = 0; r < 8; ++r) {
    float p[8];
#pragma unroll
    for (int j = 0; j < 8; ++j)
      p[j] = (qv[r][j] + bqv[r]) * (acc[r][j] + bkv[r]);
    float m = p[0];
#pragma unroll
    for (int j = 1; j < 8; ++j) m = fmaxf(m, p[j]);
    m = fmaxf(m, __shfl_xor(m, 1));
    float sl = 0.f;
#pragma unroll
    for (int j = 0; j < 8; ++j) {
      float e = __expf(p[j] - m);
      qv[r][j] = e;  // store unnormalized att
      sl += e;
    }
    sl += __shfl_xor(sl, 1);
    sden[r] = sl;
  }

  // v, then weighted sum
  gemm_tile(ws + WS_WVT, xs, r0, c0, acc);
  const float g1 = gamma1[0];
  const int n = ct * 8 + (tx >> 1);
#pragma unroll
  for (int r = 0; r < 8; ++r) {
    float p = 0.f;
#pragma unroll
    for (int j = 0; j < 8; ++j)
      p += qv[r][j] * (acc[r][j] + bvv[r]);
    p += __shfl_xor(p, 1);
    if ((tx & 1) == 0) {
      size_t oidx = ((size_t)b * NC + (r0 + r)) * NPOS + n;
      out[oidx] = x_row[oidx] + g1 * (p / sden[r]);
    }
  }
}

extern "C" void kernel_launch(void* const* d_in, const int* in_sizes, int n_in,
                              void* d_out, int out_size, void* d_ws, size_t ws_size,
                              hipStream_t stream) {
  (void)in_sizes; (void)n_in; (void)out_size; (void)ws_size;
  const float* x_row   = (const float*)d_in[0];
  const float* x_local = (const float*)d_in[1];
  const float* w0   = (const float*)d_in[2];
  const float* b0   = (const float*)d_in[3];
  const float* bn_g = (const float*)d_in[4];
  const float* bn_b = (const float*)d_in[5];
  const float* wq   = (const float*)d_in[6];
  const float* bq   = (const float*)d_in[7];
  const float* wk   = (const float*)d_in[8];
  const float* bk   = (const float*)d_in[9];
  const float* wv   = (const float*)d_in[10];
  const float* bv   = (const float*)d_in[11];
  const float* gamma1 = (const float*)d_in[12];
  float* out = (float*)d_out;
  float* ws = (float*)d_ws;

  // zero the stats accumulators (ws is poisoned before every launch)
  hipMemsetAsync(ws, 0, 2048 * sizeof(float), stream);
  k_transpose<<<256, 256, 0, stream>>>(w0, wq, wk, wv, ws);
  k_stats<<<dim3(250, NB), 256, 0, stream>>>(x_local, ws + WS_W0T, b0,
                                             ws + WS_SUM, ws + WS_SQ);
  k_fold<<<1, 128, 0, stream>>>(ws, bn_g, ws + WS_MU, ws + WS_SCALE);
  k_fused<<<dim3(250, NB), 256, 0, stream>>>(x_local, x_row, ws, b0, bn_b,
                                             bq, bk, bv, gamma1, out);
}

// Round 2
// 805.118 us; speedup vs baseline: 1.0923x; 1.0923x over previous
//
#include <hip/hip_runtime.h>
#include <math.h>

#define NB 8
#define NC 128
#define NPOS 2000
#define NK 32000
#define IN_EPS 1e-3f
#define BN_EPS 1e-5f

typedef short bf16x8 __attribute__((ext_vector_type(8)));
typedef float f32x4 __attribute__((ext_vector_type(4)));
typedef unsigned short ushort_t;

// Ht/Xt LDS row stride in ushorts (128 payload + 8 pad, keeps 16B chunk alignment,
// staggers bank groups: chunk addr = col*17 + c8 -> group (col + c8) mod 8 uniform)
#define XSTRIDE 136

__device__ __forceinline__ f32x4 mfma_bf16(bf16x8 a, bf16x8 b, f32x4 c) {
  return __builtin_amdgcn_mfma_f32_16x16x32_bf16(a, b, c, 0, 0, 0);
}

// fp32 -> bf16 round-to-nearest-even
__device__ __forceinline__ ushort_t f2bf(float f) {
  unsigned u = __float_as_uint(f);
  return (ushort_t)((u + 0x7FFFu + ((u >> 16) & 1u)) >> 16);
}

// ---- workspace layout ----
// floats: [0..1024) sum, [1024..2048) sumsq, [2048..3072) alpha, [3072..4096) beta
// then ushort bf16 weights at byte offset 16384: w0b, wqb, wkb, wvb (16384 each)

// ---------------- K0: cast weights to bf16 (natural [o][c] layout) ----------------
__global__ __launch_bounds__(256) void k_prep(const float* __restrict__ w0,
    const float* __restrict__ wq, const float* __restrict__ wk,
    const float* __restrict__ wv, ushort_t* __restrict__ wb) {
  int idx = blockIdx.x * 256 + threadIdx.x;  // 0..65535
  int m = idx >> 14;
  int e = idx & 16383;
  const float* src = (m == 0) ? w0 : (m == 1) ? wq : (m == 2) ? wk : wv;
  wb[m * 16384 + e] = f2bf(src[e]);
}

// ---- cooperative staging: Xt[col][cin] bf16 into LDS (transposed, padded) ----
__device__ __forceinline__ void stage_xt(const float* __restrict__ xb,
                                         ushort_t* __restrict__ xt, int tid) {
  const int col = tid & 127;
  const int hi = tid >> 7;  // 0/1: which half of the cin chunks
  const float* p = xb + col;
#pragma unroll
  for (int i = 0; i < 8; ++i) {
    const int c0 = hi * 64 + i * 8;
    ushort_t u[8] __attribute__((aligned(16)));
#pragma unroll
    for (int j = 0; j < 8; ++j) u[j] = f2bf(p[(size_t)(c0 + j) * NK]);
    *(uint4*)(xt + col * XSTRIDE + c0) = *(const uint4*)u;
  }
}

// ---------------- K1: conv stats (sum, sumsq of conv output, no bias) ----------------
// swapped orientation: D[m=col][n=ch], A = Xt rows, B = w0 rows (both contiguous)
__global__ __launch_bounds__(256) void k_stats(const float* __restrict__ x,
    const ushort_t* __restrict__ w0b, float* __restrict__ sum,
    float* __restrict__ sq) {
  __shared__ ushort_t xt[128 * XSTRIDE];
  const int b = blockIdx.y;
  const int col0 = blockIdx.x * 128;
  const int tid = threadIdx.x;
  stage_xt(x + (size_t)b * NC * NK + col0, xt, tid);
  __syncthreads();
  const int lane = tid & 63, w = tid >> 6;
  const int m = lane & 15, quad = lane >> 4;
  float s[8], q2[8];
#pragma unroll
  for (int rt = 0; rt < 8; ++rt) { s[rt] = 0.f; q2[rt] = 0.f; }
#pragma unroll
  for (int ct = 0; ct < 2; ++ct) {
    const int colb = w * 32 + ct * 16;
    bf16x8 af[4];
#pragma unroll
    for (int kb = 0; kb < 4; ++kb)
      af[kb] = *(const bf16x8*)(xt + (colb + m) * XSTRIDE + kb * 32 + quad * 8);
#pragma unroll
    for (int rt = 0; rt < 8; ++rt) {
      f32x4 acc = {0.f, 0.f, 0.f, 0.f};
#pragma unroll
      for (int kb = 0; kb < 4; ++kb) {
        bf16x8 bw = *(const bf16x8*)(w0b + (rt * 16 + m) * 128 + kb * 32 + quad * 8);
        acc = mfma_bf16(af[kb], bw, acc);
      }
#pragma unroll
      for (int r = 0; r < 4; ++r) {
        s[rt] += acc[r];
        q2[rt] += acc[r] * acc[r];
      }
    }
  }
  // reduce across quads (rows live in quads), then one atomic per (ch)
#pragma unroll
  for (int rt = 0; rt < 8; ++rt) {
    s[rt] += __shfl_xor(s[rt], 16);
    s[rt] += __shfl_xor(s[rt], 32);
    q2[rt] += __shfl_xor(q2[rt], 16);
    q2[rt] += __shfl_xor(q2[rt], 32);
  }
  if (quad == 0) {
#pragma unroll
    for (int rt = 0; rt < 8; ++rt) {
      atomicAdd(&sum[b * 128 + rt * 16 + m], s[rt]);
      atomicAdd(&sq[b * 128 + rt * 16 + m], q2[rt]);
    }
  }
}

// ---------------- K2: fold IN+BN into per-(b,c) alpha/beta ----------------
// conv bias b0 cancels inside IN. BN mean == 0 exactly (IN zero-means each (b,c)).
__global__ void k_fold(const float* __restrict__ ws_in, const float* __restrict__ bn_g,
                       const float* __restrict__ bn_b, float* __restrict__ alpha,
                       float* __restrict__ beta) {
  int c = threadIdx.x;  // 128 threads
  const float* sum = ws_in;
  const float* sq = ws_in + 1024;
  float var[NB], muv[NB];
  float bvar = 0.f;
#pragma unroll
  for (int b = 0; b < NB; ++b) {
    float mu = sum[b * 128 + c] * (1.f / NK);
    float v = sq[b * 128 + c] * (1.f / NK) - mu * mu;
    muv[b] = mu;
    var[b] = v;
    bvar += v / (v + IN_EPS);
  }
  bvar *= 0.125f;
  float s2 = rsqrtf(bvar + BN_EPS);
  float g = bn_g[c], bb = bn_b[c];
#pragma unroll
  for (int b = 0; b < NB; ++b) {
    float a = rsqrtf(var[b] + IN_EPS) * s2 * g;
    alpha[b * 128 + c] = a;
    beta[b * 128 + c] = bb - muv[b] * a;
  }
}

// ---------------- K3: fused conv+norm+qkv+softmax+agg ----------------
__global__ __launch_bounds__(256) void k_fused(const float* __restrict__ x,
    const float* __restrict__ x_row, const ushort_t* __restrict__ wb,
    const float* __restrict__ alpha, const float* __restrict__ beta,
    const float* __restrict__ bq, const float* __restrict__ bk,
    const float* __restrict__ bv, const float* __restrict__ g1p,
    float* __restrict__ out) {
  __shared__ ushort_t xt[128 * XSTRIDE];
  const int b = blockIdx.y;
  const int col0 = blockIdx.x * 128;
  const int tid = threadIdx.x;
  stage_xt(x + (size_t)b * NC * NK + col0, xt, tid);
  __syncthreads();
  const int lane = tid & 63, w = tid >> 6;
  const int m = lane & 15, quad = lane >> 4;
  const ushort_t* w0b = wb;
  const ushort_t* wqb = wb + 16384;
  const ushort_t* wkb = wb + 32768;
  const ushort_t* wvb = wb + 49152;
  const float g1 = g1p[0];
  const float* al = alpha + b * 128;
  const float* be = beta + b * 128;

#pragma unroll 1
  for (int ct = 0; ct < 2; ++ct) {
    const int colb = w * 32 + ct * 16;       // wave-private 16-col tile == one position n
    ushort_t* xrow = xt + (colb + m) * XSTRIDE;

    // ---- H = w0 @ x : standard orientation, D[ch][col] ----
    bf16x8 bfX[4];
#pragma unroll
    for (int kb = 0; kb < 4; ++kb)
      bfX[kb] = *(const bf16x8*)(xrow + kb * 32 + quad * 8);
    f32x4 hf[8];
#pragma unroll
    for (int rt = 0; rt < 8; ++rt) {
      f32x4 acc = {0.f, 0.f, 0.f, 0.f};
#pragma unroll
      for (int kb = 0; kb < 4; ++kb) {
        bf16x8 aw = *(const bf16x8*)(w0b + (rt * 16 + m) * 128 + kb * 32 + quad * 8);
        acc = mfma_bf16(aw, bfX[kb], acc);
      }
      hf[rt] = acc;
    }

    // ---- norm + relu, pack bf16, overwrite this wave's LDS cols with Ht ----
#pragma unroll
    for (int rt = 0; rt < 8; ++rt) {
      const float4 av = *(const float4*)(al + rt * 16 + quad * 4);
      const float4 bev = *(const float4*)(be + rt * 16 + quad * 4);
      float h0 = fmaxf(hf[rt][0] * av.x + bev.x, 0.f);
      float h1 = fmaxf(hf[rt][1] * av.y + bev.y, 0.f);
      float h2 = fmaxf(hf[rt][2] * av.z + bev.z, 0.f);
      float h3 = fmaxf(hf[rt][3] * av.w + bev.w, 0.f);
      uint2 pk;
      pk.x = (unsigned)f2bf(h0) | ((unsigned)f2bf(h1) << 16);
      pk.y = (unsigned)f2bf(h2) | ((unsigned)f2bf(h3) << 16);
      *(uint2*)(xrow + rt * 16 + quad * 4) = pk;  // Ht[col][ch], ch = rt*16+quad*4
    }

    // ---- A-fragments of Hn, shared by Q/K/V (same-wave LDS is in-order) ----
    bf16x8 afH[4];
#pragma unroll
    for (int kb = 0; kb < 4; ++kb)
      afH[kb] = *(const bf16x8*)(xrow + kb * 32 + quad * 8);

    // ---- Q, K GEMMs: swapped orientation, D[neigh][ch] ----
    f32x4 qf[8], kf[8];
#pragma unroll
    for (int rt = 0; rt < 8; ++rt) {
      f32x4 acc = {0.f, 0.f, 0.f, 0.f};
#pragma unroll
      for (int kb = 0; kb < 4; ++kb) {
        bf16x8 bw = *(const bf16x8*)(wqb + (rt * 16 + m) * 128 + kb * 32 + quad * 8);
        acc = mfma_bf16(afH[kb], bw, acc);
      }
      qf[rt] = acc;
    }
#pragma unroll
    for (int rt = 0; rt < 8; ++rt) {
      f32x4 acc = {0.f, 0.f, 0.f, 0.f};
#pragma unroll
      for (int kb = 0; kb < 4; ++kb) {
        bf16x8 bw = *(const bf16x8*)(wkb + (rt * 16 + m) * 128 + kb * 32 + quad * 8);
        acc = mfma_bf16(afH[kb], bw, acc);
      }
      kf[rt] = acc;
    }

    // ---- softmax over 16 neighbors = 4 regs (rows) + quads ----
#pragma unroll
    for (int rt = 0; rt < 8; ++rt) {
      const float bqs = bq[rt * 16 + m];
      const float bks = bk[rt * 16 + m];
      float p0 = (qf[rt][0] + bqs) * (kf[rt][0] + bks);
      float p1 = (qf[rt][1] + bqs) * (kf[rt][1] + bks);
      float p2 = (qf[rt][2] + bqs) * (kf[rt][2] + bks);
      float p3 = (qf[rt][3] + bqs) * (kf[rt][3] + bks);
      float mx = fmaxf(fmaxf(p0, p1), fmaxf(p2, p3));
      mx = fmaxf(mx, __shfl_xor(mx, 16));
      mx = fmaxf(mx, __shfl_xor(mx, 32));
      float e0 = __expf(p0 - mx), e1 = __expf(p1 - mx);
      float e2 = __expf(p2 - mx), e3 = __expf(p3 - mx);
      float sm = (e0 + e1) + (e2 + e3);
      sm += __shfl_xor(sm, 16);
      sm += __shfl_xor(sm, 32);
      float inv = 1.0f / sm;
      qf[rt][0] = e0 * inv;  // att stored back in qf
      qf[rt][1] = e1 * inv;
      qf[rt][2] = e2 * inv;
      qf[rt][3] = e3 * inv;
    }

    // ---- V GEMM + weighted aggregation + residual write ----
#pragma unroll
    for (int rt = 0; rt < 8; ++rt) {
      f32x4 acc = {0.f, 0.f, 0.f, 0.f};
#pragma unroll
      for (int kb = 0; kb < 4; ++kb) {
        bf16x8 bw = *(const bf16x8*)(wvb + (rt * 16 + m) * 128 + kb * 32 + quad * 8);
        acc = mfma_bf16(afH[kb], bw, acc);
      }
      const float bvs = bv[rt * 16 + m];
      float r0 = qf[rt][0] * (acc[0] + bvs) + qf[rt][1] * (acc[1] + bvs) +
                 qf[rt][2] * (acc[2] + bvs) + qf[rt][3] * (acc[3] + bvs);
      r0 += __shfl_xor(r0, 16);
      r0 += __shfl_xor(r0, 32);
      if (quad == 0) {
        const int n = (col0 + colb) >> 4;
        const size_t oi = ((size_t)b * NC + rt * 16 + m) * NPOS + n;
        out[oi] = x_row[oi] + g1 * r0;
      }
    }
  }
}

extern "C" void kernel_launch(void* const* d_in, const int* in_sizes, int n_in,
                              void* d_out, int out_size, void* d_ws, size_t ws_size,
                              hipStream_t stream) {
  (void)in_sizes; (void)n_in; (void)out_size; (void)ws_size;
  const float* x_row   = (const float*)d_in[0];
  const float* x_local = (const float*)d_in[1];
  const float* w0   = (const float*)d_in[2];
  const float* bn_g = (const float*)d_in[4];
  const float* bn_b = (const float*)d_in[5];
  const float* wq   = (const float*)d_in[6];
  const float* bq   = (const float*)d_in[7];
  const float* wk   = (const float*)d_in[8];
  const float* bk   = (const float*)d_in[9];
  const float* wv   = (const float*)d_in[10];
  const float* bv   = (const float*)d_in[11];
  const float* gamma1 = (const float*)d_in[12];
  float* out = (float*)d_out;
  float* ws = (float*)d_ws;
  ushort_t* wb = (ushort_t*)((char*)d_ws + 16384);

  hipMemsetAsync(ws, 0, 2048 * sizeof(float), stream);  // sum/sumsq accumulators
  k_prep<<<256, 256, 0, stream>>>(w0, wq, wk, wv, wb);
  k_stats<<<dim3(250, NB), 256, 0, stream>>>(x_local, wb, ws, ws + 1024);
  k_fold<<<1, 128, 0, stream>>>(ws, bn_g, bn_b, ws + 2048, ws + 3072);
  k_fused<<<dim3(250, NB), 256, 0, stream>>>(x_local, x_row, wb, ws + 2048,
                                             ws + 3072, bq, bk, bv, gamma1, out);
}

// Round 3
// 743.327 us; speedup vs baseline: 1.1831x; 1.0831x over previous
//
#include <hip/hip_runtime.h>
#include <math.h>

#define NB 8
#define NC 128
#define NPOS 2000
#define NK 32000
#define IN_EPS 1e-3f
#define BN_EPS 1e-5f

typedef short bf16x8 __attribute__((ext_vector_type(8)));
typedef float f32x4 __attribute__((ext_vector_type(4)));
typedef unsigned short ushort_t;

// Xt/Ht LDS row stride in ushorts (128 payload + 8 pad -> 2-way bank aliasing max, free)
#define XSTRIDE 136

__device__ __forceinline__ f32x4 mfma_bf16(bf16x8 a, bf16x8 b, f32x4 c) {
  return __builtin_amdgcn_mfma_f32_16x16x32_bf16(a, b, c, 0, 0, 0);
}

// fp32 -> bf16 round-to-nearest-even
__device__ __forceinline__ ushort_t f2bf(float f) {
  unsigned u = __float_as_uint(f);
  return (ushort_t)((u + 0x7FFFu + ((u >> 16) & 1u)) >> 16);
}

// ---- workspace layout ----
// floats: [0..1024) sum, [1024..2048) sumsq, [2048..3072) alpha, [3072..4096) beta
// then ushort bf16 weights at byte offset 16384: w0b, wqb, wkb, wvb (16384 elems each)

// ---------------- K0: cast weights to bf16 (natural [o][c] layout) ----------------
__global__ __launch_bounds__(256) void k_prep(const float* __restrict__ w0,
    const float* __restrict__ wq, const float* __restrict__ wk,
    const float* __restrict__ wv, ushort_t* __restrict__ wb) {
  int idx = blockIdx.x * 256 + threadIdx.x;  // 0..65535
  int m = idx >> 14;
  int e = idx & 16383;
  const float* src = (m == 0) ? w0 : (m == 1) ? wq : (m == 2) ? wk : wv;
  wb[m * 16384 + e] = f2bf(src[e]);
}

// ---- cooperative staging: Xt[col][cin] bf16 into LDS (transposed, padded) ----
__device__ __forceinline__ void stage_xt(const float* __restrict__ xb,
                                         ushort_t* __restrict__ xt, int tid) {
  const int col = tid & 127;
  const int hi = tid >> 7;  // 0/1: which half of the cin chunks
  const float* p = xb + col;
#pragma unroll
  for (int i = 0; i < 8; ++i) {
    const int c0 = hi * 64 + i * 8;
    ushort_t u[8] __attribute__((aligned(16)));
#pragma unroll
    for (int j = 0; j < 8; ++j) u[j] = f2bf(p[(size_t)(c0 + j) * NK]);
    *(uint4*)(xt + col * XSTRIDE + c0) = *(const uint4*)u;
  }
}

// ---------------- K1: conv stats (sum, sumsq of conv output, no bias) ----------------
// swapped orientation: D[m=col][n=ch], A = Xt rows, B = w0 rows (both contiguous)
__global__ __launch_bounds__(256) void k_stats(const float* __restrict__ x,
    const ushort_t* __restrict__ w0b, float* __restrict__ sum,
    float* __restrict__ sq) {
  __shared__ ushort_t xt[128 * XSTRIDE];
  const int b = blockIdx.y;
  const int col0 = blockIdx.x * 128;
  const int tid = threadIdx.x;
  stage_xt(x + (size_t)b * NC * NK + col0, xt, tid);
  __syncthreads();
  const int lane = tid & 63, w = tid >> 6;
  const int m = lane & 15, quad = lane >> 4;
  float s[8], q2[8];
#pragma unroll
  for (int rt = 0; rt < 8; ++rt) { s[rt] = 0.f; q2[rt] = 0.f; }
#pragma unroll 1
  for (int ct = 0; ct < 2; ++ct) {
    const int colb = w * 32 + ct * 16;
    bf16x8 af[4];
#pragma unroll
    for (int kb = 0; kb < 4; ++kb)
      af[kb] = *(const bf16x8*)(xt + (colb + m) * XSTRIDE + kb * 32 + quad * 8);
#pragma unroll
    for (int rt = 0; rt < 8; ++rt) {
      f32x4 acc = {0.f, 0.f, 0.f, 0.f};
#pragma unroll
      for (int kb = 0; kb < 4; ++kb) {
        bf16x8 bw = *(const bf16x8*)(w0b + (rt * 16 + m) * 128 + kb * 32 + quad * 8);
        acc = mfma_bf16(af[kb], bw, acc);
      }
#pragma unroll
      for (int r = 0; r < 4; ++r) {
        s[rt] += acc[r];
        q2[rt] += acc[r] * acc[r];
      }
    }
  }
  // reduce across quads (rows live in quads), then one atomic per channel
#pragma unroll
  for (int rt = 0; rt < 8; ++rt) {
    s[rt] += __shfl_xor(s[rt], 16);
    s[rt] += __shfl_xor(s[rt], 32);
    q2[rt] += __shfl_xor(q2[rt], 16);
    q2[rt] += __shfl_xor(q2[rt], 32);
  }
  if (quad == 0) {
#pragma unroll
    for (int rt = 0; rt < 8; ++rt) {
      atomicAdd(&sum[b * 128 + rt * 16 + m], s[rt]);
      atomicAdd(&sq[b * 128 + rt * 16 + m], q2[rt]);
    }
  }
}

// ---------------- K2: fold IN+BN into per-(b,c) alpha/beta ----------------
// conv bias b0 cancels inside IN. BN mean == 0 exactly (IN zero-means each (b,c)).
__global__ void k_fold(const float* __restrict__ ws_in, const float* __restrict__ bn_g,
                       const float* __restrict__ bn_b, float* __restrict__ alpha,
                       float* __restrict__ beta) {
  int c = threadIdx.x;  // 128 threads
  const float* sum = ws_in;
  const float* sq = ws_in + 1024;
  float var[NB], muv[NB];
  float bvar = 0.f;
#pragma unroll
  for (int b = 0; b < NB; ++b) {
    float mu = sum[b * 128 + c] * (1.f / NK);
    float v = sq[b * 128 + c] * (1.f / NK) - mu * mu;
    muv[b] = mu;
    var[b] = v;
    bvar += v / (v + IN_EPS);
  }
  bvar *= 0.125f;
  float s2 = rsqrtf(bvar + BN_EPS);
  float g = bn_g[c], bb = bn_b[c];
#pragma unroll
  for (int b = 0; b < NB; ++b) {
    float a = rsqrtf(var[b] + IN_EPS) * s2 * g;
    alpha[b * 128 + c] = a;
    beta[b * 128 + c] = bb - muv[b] * a;
  }
}

// ---------------- K3: fused conv+norm+qkv+softmax+agg ----------------
// Per-16-channel-strip streaming: never hold more than one strip's accumulators.
__global__ __launch_bounds__(256) void k_fused(const float* __restrict__ x,
    const float* __restrict__ x_row, const ushort_t* __restrict__ wb,
    const float* __restrict__ alpha, const float* __restrict__ beta,
    const float* __restrict__ bq, const float* __restrict__ bk,
    const float* __restrict__ bv, const float* __restrict__ g1p,
    float* __restrict__ out) {
  __shared__ ushort_t xt[128 * XSTRIDE];
  __shared__ float als[128], bes[128], bqs[128], bks[128], bvs[128];
  const int b = blockIdx.y;
  const int col0 = blockIdx.x * 128;
  const int tid = threadIdx.x;
  stage_xt(x + (size_t)b * NC * NK + col0, xt, tid);
  if (tid < 128) {
    als[tid] = alpha[b * 128 + tid];
    bes[tid] = beta[b * 128 + tid];
    bqs[tid] = bq[tid];
    bks[tid] = bk[tid];
    bvs[tid] = bv[tid];
  }
  __syncthreads();
  const int lane = tid & 63, w = tid >> 6;
  const int m = lane & 15, quad = lane >> 4;
  const ushort_t* w0b = wb;
  const ushort_t* wqb = wb + 16384;
  const ushort_t* wkb = wb + 32768;
  const ushort_t* wvb = wb + 49152;
  const float g1 = g1p[0];

#pragma unroll 1
  for (int ct = 0; ct < 2; ++ct) {
    const int colb = w * 32 + ct * 16;  // wave-private 16-col tile == one position n
    ushort_t* xrow = xt + (colb + m) * XSTRIDE;

    // ---- H = w0 @ x, one 16-ch strip at a time; normalize+relu+pack -> LDS ----
    bf16x8 bfX[4];
#pragma unroll
    for (int kb = 0; kb < 4; ++kb)
      bfX[kb] = *(const bf16x8*)(xrow + kb * 32 + quad * 8);
#pragma unroll
    for (int rt = 0; rt < 8; ++rt) {
      f32x4 acc = {0.f, 0.f, 0.f, 0.f};
#pragma unroll
      for (int kb = 0; kb < 4; ++kb) {
        bf16x8 aw = *(const bf16x8*)(w0b + (rt * 16 + m) * 128 + kb * 32 + quad * 8);
        acc = mfma_bf16(aw, bfX[kb], acc);
      }
      const float4 av = *(const float4*)(als + rt * 16 + quad * 4);
      const float4 bev = *(const float4*)(bes + rt * 16 + quad * 4);
      float h0 = fmaxf(acc[0] * av.x + bev.x, 0.f);
      float h1 = fmaxf(acc[1] * av.y + bev.y, 0.f);
      float h2 = fmaxf(acc[2] * av.z + bev.z, 0.f);
      float h3 = fmaxf(acc[3] * av.w + bev.w, 0.f);
      uint2 pk;
      pk.x = (unsigned)f2bf(h0) | ((unsigned)f2bf(h1) << 16);
      pk.y = (unsigned)f2bf(h2) | ((unsigned)f2bf(h3) << 16);
      *(uint2*)(xrow + rt * 16 + quad * 4) = pk;  // Ht[col][ch]
    }

    // ---- A-fragments of normalized H, shared by Q/K/V ----
    bf16x8 afH[4];
#pragma unroll
    for (int kb = 0; kb < 4; ++kb)
      afH[kb] = *(const bf16x8*)(xrow + kb * 32 + quad * 8);

    // ---- per-strip fused Q,K -> softmax -> V -> aggregate -> write ----
#pragma unroll
    for (int rt = 0; rt < 8; ++rt) {
      f32x4 qa = {0.f, 0.f, 0.f, 0.f};
#pragma unroll
      for (int kb = 0; kb < 4; ++kb) {
        bf16x8 bw = *(const bf16x8*)(wqb + (rt * 16 + m) * 128 + kb * 32 + quad * 8);
        qa = mfma_bf16(afH[kb], bw, qa);
      }
      f32x4 ka = {0.f, 0.f, 0.f, 0.f};
#pragma unroll
      for (int kb = 0; kb < 4; ++kb) {
        bf16x8 bw = *(const bf16x8*)(wkb + (rt * 16 + m) * 128 + kb * 32 + quad * 8);
        ka = mfma_bf16(afH[kb], bw, ka);
      }
      const float bqv = bqs[rt * 16 + m];
      const float bkv = bks[rt * 16 + m];
      float p0 = (qa[0] + bqv) * (ka[0] + bkv);
      float p1 = (qa[1] + bqv) * (ka[1] + bkv);
      float p2 = (qa[2] + bqv) * (ka[2] + bkv);
      float p3 = (qa[3] + bqv) * (ka[3] + bkv);
      float mx = fmaxf(fmaxf(p0, p1), fmaxf(p2, p3));
      mx = fmaxf(mx, __shfl_xor(mx, 16));
      mx = fmaxf(mx, __shfl_xor(mx, 32));
      float e0 = __expf(p0 - mx), e1 = __expf(p1 - mx);
      float e2 = __expf(p2 - mx), e3 = __expf(p3 - mx);
      float sm = (e0 + e1) + (e2 + e3);
      sm += __shfl_xor(sm, 16);
      sm += __shfl_xor(sm, 32);
      f32x4 va = {0.f, 0.f, 0.f, 0.f};
#pragma unroll
      for (int kb = 0; kb < 4; ++kb) {
        bf16x8 bw = *(const bf16x8*)(wvb + (rt * 16 + m) * 128 + kb * 32 + quad * 8);
        va = mfma_bf16(afH[kb], bw, va);
      }
      const float bvv = bvs[rt * 16 + m];
      float r0 = e0 * (va[0] + bvv) + e1 * (va[1] + bvv) +
                 e2 * (va[2] + bvv) + e3 * (va[3] + bvv);
      r0 += __shfl_xor(r0, 16);
      r0 += __shfl_xor(r0, 32);
      if (quad == 0) {
        const int n = (col0 + colb) >> 4;
        const size_t oi = ((size_t)b * NC + rt * 16 + m) * NPOS + n;
        out[oi] = x_row[oi] + g1 * (r0 / sm);
      }
    }
  }
}

extern "C" void kernel_launch(void* const* d_in, const int* in_sizes, int n_in,
                              void* d_out, int out_size, void* d_ws, size_t ws_size,
                              hipStream_t stream) {
  (void)in_sizes; (void)n_in; (void)out_size; (void)ws_size;
  const float* x_row   = (const float*)d_in[0];
  const float* x_local = (const float*)d_in[1];
  const float* w0   = (const float*)d_in[2];
  const float* bn_g = (const float*)d_in[4];
  const float* bn_b = (const float*)d_in[5];
  const float* wq   = (const float*)d_in[6];
  const float* bq   = (const float*)d_in[7];
  const float* wk   = (const float*)d_in[8];
  const float* bk   = (const float*)d_in[9];
  const float* wv   = (const float*)d_in[10];
  const float* bv   = (const float*)d_in[11];
  const float* gamma1 = (const float*)d_in[12];
  float* out = (float*)d_out;
  float* ws = (float*)d_ws;
  ushort_t* wb = (ushort_t*)((char*)d_ws + 16384);

  hipMemsetAsync(ws, 0, 2048 * sizeof(float), stream);  // sum/sumsq accumulators
  k_prep<<<256, 256, 0, stream>>>(w0, wq, wk, wv, wb);
  k_stats<<<dim3(250, NB), 256, 0, stream>>>(x_local, wb, ws, ws + 1024);
  k_fold<<<1, 128, 0, stream>>>(ws, bn_g, bn_b, ws + 2048, ws + 3072);
  k_fused<<<dim3(250, NB), 256, 0, stream>>>(x_local, x_row, wb, ws + 2048,
                                             ws + 3072, bq, bk, bv, gamma1, out);
}

// Round 4
// 542.963 us; speedup vs baseline: 1.6197x; 1.3690x over previous
//
#include <hip/hip_runtime.h>
#include <math.h>

#define NB 8
#define NC 128
#define NPOS 2000
#define NK 32000
#define IN_EPS 1e-3f
#define BN_EPS 1e-5f

typedef short bf16x8 __attribute__((ext_vector_type(8)));
typedef float f32x4 __attribute__((ext_vector_type(4)));
typedef unsigned short ushort_t;

// Xt/Ht LDS row stride in ushorts (128 payload + 8 pad; 272B rows keep 16B alignment,
// 2-way bank aliasing max which is free)
#define XSTRIDE 136

__device__ __forceinline__ f32x4 mfma_bf16(bf16x8 a, bf16x8 b, f32x4 c) {
  return __builtin_amdgcn_mfma_f32_16x16x32_bf16(a, b, c, 0, 0, 0);
}

// fp32 -> bf16 round-to-nearest-even
__device__ __forceinline__ ushort_t f2bf(float f) {
  unsigned u = __float_as_uint(f);
  return (ushort_t)((u + 0x7FFFu + ((u >> 16) & 1u)) >> 16);
}

// ---- workspace layout ----
// floats: [0..1024) sum, [1024..2048) sumsq, [2048..3072) alpha, [3072..4096) beta
// then ushort bf16 weights at byte offset 16384: w0b, wqb, wkb, wvb (16384 elems each)

// ---------------- K0: cast weights to bf16 (natural [o][c] layout) ----------------
__global__ __launch_bounds__(256) void k_prep(const float* __restrict__ w0,
    const float* __restrict__ wq, const float* __restrict__ wk,
    const float* __restrict__ wv, ushort_t* __restrict__ wb) {
  int idx = blockIdx.x * 256 + threadIdx.x;  // 0..65535
  int m = idx >> 14;
  int e = idx & 16383;
  const float* src = (m == 0) ? w0 : (m == 1) ? wq : (m == 2) ? wk : wv;
  wb[m * 16384 + e] = f2bf(src[e]);
}

// ---- cooperative staging: Xt[col][cin] bf16 into LDS (transposed, padded) ----
__device__ __forceinline__ void stage_xt(const float* __restrict__ xb,
                                         ushort_t* __restrict__ xt, int tid) {
  const int col = tid & 127;
  const int hi = tid >> 7;  // 0/1: which half of the cin chunks
  const float* p = xb + col;
#pragma unroll
  for (int i = 0; i < 8; ++i) {
    const int c0 = hi * 64 + i * 8;
    ushort_t u[8] __attribute__((aligned(16)));
#pragma unroll
    for (int j = 0; j < 8; ++j) u[j] = f2bf(p[(size_t)(c0 + j) * NK]);
    *(uint4*)(xt + col * XSTRIDE + c0) = *(const uint4*)u;
  }
}

// ---------------- K1: conv stats (sum, sumsq of conv output, no bias) ----------------
// swapped orientation: D[m=col][n=ch], A = Xt rows, B = w0 rows (both contiguous)
__global__ __launch_bounds__(256, 4) void k_stats(const float* __restrict__ x,
    const ushort_t* __restrict__ w0b, float* __restrict__ sum,
    float* __restrict__ sq) {
  __shared__ ushort_t xt[128 * XSTRIDE];
  __shared__ float ssum[128], ssq[128];
  const int b = blockIdx.y;
  const int col0 = blockIdx.x * 128;
  const int tid = threadIdx.x;
  if (tid < 128) { ssum[tid] = 0.f; ssq[tid] = 0.f; }
  stage_xt(x + (size_t)b * NC * NK + col0, xt, tid);
  __syncthreads();
  const int lane = tid & 63, w = tid >> 6;
  const int m = lane & 15, quad = lane >> 4;
#pragma unroll 1
  for (int ct = 0; ct < 2; ++ct) {
    const int colb = w * 32 + ct * 16;
    bf16x8 af[4];
#pragma unroll
    for (int kb = 0; kb < 4; ++kb)
      af[kb] = *(const bf16x8*)(xt + (colb + m) * XSTRIDE + kb * 32 + quad * 8);
#pragma unroll 2
    for (int rt = 0; rt < 8; ++rt) {
      f32x4 acc = {0.f, 0.f, 0.f, 0.f};
#pragma unroll
      for (int kb = 0; kb < 4; ++kb) {
        bf16x8 bw = *(const bf16x8*)(w0b + (rt * 16 + m) * 128 + kb * 32 + quad * 8);
        acc = mfma_bf16(af[kb], bw, acc);
      }
      float s = (acc[0] + acc[1]) + (acc[2] + acc[3]);
      float q2 = (acc[0] * acc[0] + acc[1] * acc[1]) +
                 (acc[2] * acc[2] + acc[3] * acc[3]);
      s += __shfl_xor(s, 16);
      s += __shfl_xor(s, 32);
      q2 += __shfl_xor(q2, 16);
      q2 += __shfl_xor(q2, 32);
      if (quad == 0) {
        atomicAdd(&ssum[rt * 16 + m], s);
        atomicAdd(&ssq[rt * 16 + m], q2);
      }
    }
  }
  __syncthreads();
  if (tid < 128) {
    atomicAdd(&sum[b * 128 + tid], ssum[tid]);
    atomicAdd(&sq[b * 128 + tid], ssq[tid]);
  }
}

// ---------------- K2: fold IN+BN into per-(b,c) alpha/beta ----------------
// conv bias b0 cancels inside IN. BN mean == 0 exactly (IN zero-means each (b,c)).
__global__ void k_fold(const float* __restrict__ ws_in, const float* __restrict__ bn_g,
                       const float* __restrict__ bn_b, float* __restrict__ alpha,
                       float* __restrict__ beta) {
  int c = threadIdx.x;  // 128 threads
  const float* sum = ws_in;
  const float* sq = ws_in + 1024;
  float var[NB], muv[NB];
  float bvar = 0.f;
#pragma unroll
  for (int b = 0; b < NB; ++b) {
    float mu = sum[b * 128 + c] * (1.f / NK);
    float v = sq[b * 128 + c] * (1.f / NK) - mu * mu;
    muv[b] = mu;
    var[b] = v;
    bvar += v / (v + IN_EPS);
  }
  bvar *= 0.125f;
  float s2 = rsqrtf(bvar + BN_EPS);
  float g = bn_g[c], bb = bn_b[c];
#pragma unroll
  for (int b = 0; b < NB; ++b) {
    float a = rsqrtf(var[b] + IN_EPS) * s2 * g;
    alpha[b * 128 + c] = a;
    beta[b * 128 + c] = bb - muv[b] * a;
  }
}

// ---------------- K3: fused conv+norm+qkv+softmax+agg ----------------
// Per-16-channel-strip streaming; rt loops kept rolled (unroll 1) so weight-load
// prefetch cannot blow the register file. VGPR capped at 128 via launch_bounds.
__global__ __launch_bounds__(256, 4) void k_fused(const float* __restrict__ x,
    const float* __restrict__ x_row, const ushort_t* __restrict__ wb,
    const float* __restrict__ alpha, const float* __restrict__ beta,
    const float* __restrict__ bq, const float* __restrict__ bk,
    const float* __restrict__ bv, const float* __restrict__ g1p,
    float* __restrict__ out) {
  __shared__ ushort_t xt[128 * XSTRIDE];
  __shared__ float als[128], bes[128], bqs[128], bks[128], bvs[128];
  __shared__ float souts[128 * 9];  // [ch][pos], pad 9 to kill bank conflicts
  const int b = blockIdx.y;
  const int col0 = blockIdx.x * 128;
  const int tid = threadIdx.x;
  stage_xt(x + (size_t)b * NC * NK + col0, xt, tid);
  if (tid < 128) {
    als[tid] = alpha[b * 128 + tid];
    bes[tid] = beta[b * 128 + tid];
    bqs[tid] = bq[tid];
    bks[tid] = bk[tid];
    bvs[tid] = bv[tid];
  }
  __syncthreads();
  const int lane = tid & 63, w = tid >> 6;
  const int m = lane & 15, quad = lane >> 4;
  const ushort_t* w0b = wb;
  const ushort_t* wqb = wb + 16384;
  const ushort_t* wkb = wb + 32768;
  const ushort_t* wvb = wb + 49152;

#pragma unroll 1
  for (int ct = 0; ct < 2; ++ct) {
    const int colb = w * 32 + ct * 16;  // wave-private 16-col tile == one position n
    ushort_t* xrow = xt + (colb + m) * XSTRIDE;

    // ---- H = w0 @ x, one 16-ch strip at a time; normalize+relu+pack -> LDS ----
    bf16x8 bfX[4];
#pragma unroll
    for (int kb = 0; kb < 4; ++kb)
      bfX[kb] = *(const bf16x8*)(xrow + kb * 32 + quad * 8);
#pragma unroll 1
    for (int rt = 0; rt < 8; ++rt) {
      f32x4 acc = {0.f, 0.f, 0.f, 0.f};
#pragma unroll
      for (int kb = 0; kb < 4; ++kb) {
        bf16x8 aw = *(const bf16x8*)(w0b + (rt * 16 + m) * 128 + kb * 32 + quad * 8);
        acc = mfma_bf16(aw, bfX[kb], acc);
      }
      const float4 av = *(const float4*)(als + rt * 16 + quad * 4);
      const float4 bev = *(const float4*)(bes + rt * 16 + quad * 4);
      float h0 = fmaxf(acc[0] * av.x + bev.x, 0.f);
      float h1 = fmaxf(acc[1] * av.y + bev.y, 0.f);
      float h2 = fmaxf(acc[2] * av.z + bev.z, 0.f);
      float h3 = fmaxf(acc[3] * av.w + bev.w, 0.f);
      uint2 pk;
      pk.x = (unsigned)f2bf(h0) | ((unsigned)f2bf(h1) << 16);
      pk.y = (unsigned)f2bf(h2) | ((unsigned)f2bf(h3) << 16);
      *(uint2*)(xrow + rt * 16 + quad * 4) = pk;  // Ht[col][ch]
    }

    // ---- A-fragments of normalized H, shared by Q/K/V ----
    bf16x8 afH[4];
#pragma unroll
    for (int kb = 0; kb < 4; ++kb)
      afH[kb] = *(const bf16x8*)(xrow + kb * 32 + quad * 8);

    // ---- per-strip fused Q,K -> softmax -> V -> aggregate -> stash in LDS ----
#pragma unroll 1
    for (int rt = 0; rt < 8; ++rt) {
      f32x4 qa = {0.f, 0.f, 0.f, 0.f};
      f32x4 ka = {0.f, 0.f, 0.f, 0.f};
      f32x4 va = {0.f, 0.f, 0.f, 0.f};
#pragma unroll
      for (int kb = 0; kb < 4; ++kb) {
        bf16x8 bw = *(const bf16x8*)(wqb + (rt * 16 + m) * 128 + kb * 32 + quad * 8);
        qa = mfma_bf16(afH[kb], bw, qa);
      }
#pragma unroll
      for (int kb = 0; kb < 4; ++kb) {
        bf16x8 bw = *(const bf16x8*)(wkb + (rt * 16 + m) * 128 + kb * 32 + quad * 8);
        ka = mfma_bf16(afH[kb], bw, ka);
      }
      const float bqv = bqs[rt * 16 + m];
      const float bkv = bks[rt * 16 + m];
      float p0 = (qa[0] + bqv) * (ka[0] + bkv);
      float p1 = (qa[1] + bqv) * (ka[1] + bkv);
      float p2 = (qa[2] + bqv) * (ka[2] + bkv);
      float p3 = (qa[3] + bqv) * (ka[3] + bkv);
      float mx = fmaxf(fmaxf(p0, p1), fmaxf(p2, p3));
      mx = fmaxf(mx, __shfl_xor(mx, 16));
      mx = fmaxf(mx, __shfl_xor(mx, 32));
      float e0 = __expf(p0 - mx), e1 = __expf(p1 - mx);
      float e2 = __expf(p2 - mx), e3 = __expf(p3 - mx);
      float sm = (e0 + e1) + (e2 + e3);
      sm += __shfl_xor(sm, 16);
      sm += __shfl_xor(sm, 32);
#pragma unroll
      for (int kb = 0; kb < 4; ++kb) {
        bf16x8 bw = *(const bf16x8*)(wvb + (rt * 16 + m) * 128 + kb * 32 + quad * 8);
        va = mfma_bf16(afH[kb], bw, va);
      }
      const float bvv = bvs[rt * 16 + m];
      float r0 = e0 * (va[0] + bvv) + e1 * (va[1] + bvv) +
                 e2 * (va[2] + bvv) + e3 * (va[3] + bvv);
      r0 += __shfl_xor(r0, 16);
      r0 += __shfl_xor(r0, 32);
      if (quad == 0) souts[(rt * 16 + m) * 9 + (colb >> 4)] = r0 / sm;
    }
  }
  __syncthreads();

  // ---- coalesced epilogue: out = x_row + g1 * souts ----
  {
    const float g1 = g1p[0];
    const int c = tid >> 1, half = tid & 1;
    const int n0 = blockIdx.x * 8 + half * 4;
    const size_t oi = ((size_t)b * NC + c) * NPOS + n0;
    const float4 xr = *(const float4*)(x_row + oi);
    const float* sp = souts + c * 9 + half * 4;
    float4 o;
    o.x = xr.x + g1 * sp[0];
    o.y = xr.y + g1 * sp[1];
    o.z = xr.z + g1 * sp[2];
    o.w = xr.w + g1 * sp[3];
    *(float4*)(out + oi) = o;
  }
}

extern "C" void kernel_launch(void* const* d_in, const int* in_sizes, int n_in,
                              void* d_out, int out_size, void* d_ws, size_t ws_size,
                              hipStream_t stream) {
  (void)in_sizes; (void)n_in; (void)out_size; (void)ws_size;
  const float* x_row   = (const float*)d_in[0];
  const float* x_local = (const float*)d_in[1];
  const float* w0   = (const float*)d_in[2];
  const float* bn_g = (const float*)d_in[4];
  const float* bn_b = (const float*)d_in[5];
  const float* wq   = (const float*)d_in[6];
  const float* bq   = (const float*)d_in[7];
  const float* wk   = (const float*)d_in[8];
  const float* bk   = (const float*)d_in[9];
  const float* wv   = (const float*)d_in[10];
  const float* bv   = (const float*)d_in[11];
  const float* gamma1 = (const float*)d_in[12];
  float* out = (float*)d_out;
  float* ws = (float*)d_ws;
  ushort_t* wb = (ushort_t*)((char*)d_ws + 16384);

  hipMemsetAsync(ws, 0, 2048 * sizeof(float), stream);  // sum/sumsq accumulators
  k_prep<<<256, 256, 0, stream>>>(w0, wq, wk, wv, wb);
  k_stats<<<dim3(250, NB), 256, 0, stream>>>(x_local, wb, ws, ws + 1024);
  k_fold<<<1, 128, 0, stream>>>(ws, bn_g, bn_b, ws + 2048, ws + 3072);
  k_fused<<<dim3(250, NB), 256, 0, stream>>>(x_local, x_row, wb, ws + 2048,
                                             ws + 3072, bq, bk, bv, gamma1, out);
}

// Round 5
// 317.605 us; speedup vs baseline: 2.7690x; 1.7096x over previous
//
#include <hip/hip_runtime.h>
#include <math.h>

#define NB 8
#define NC 128
#define NPOS 2000
#define NK 32000
#define IN_EPS 1e-3f
#define BN_EPS 1e-5f

typedef short bf16x8 __attribute__((ext_vector_type(8)));
typedef float f32x4 __attribute__((ext_vector_type(4)));
typedef unsigned short ushort_t;

// Xt/Ht LDS row stride in ushorts (128 payload + 8 pad; keeps 16B alignment)
#define XSTRIDE 136

__device__ __forceinline__ f32x4 mfma_bf16(bf16x8 a, bf16x8 b, f32x4 c) {
  return __builtin_amdgcn_mfma_f32_16x16x32_bf16(a, b, c, 0, 0, 0);
}

// fp32 -> bf16 round-to-nearest-even
__device__ __forceinline__ ushort_t f2bf(float f) {
  unsigned u = __float_as_uint(f);
  return (ushort_t)((u + 0x7FFFu + ((u >> 16) & 1u)) >> 16);
}

// ---- workspace layout ----
// floats: [0..1024) sum, [1024..2048) sumsq, [2048..3072) alpha, [3072..4096) beta
// then ushort bf16 weights at byte offset 16384: w0b, wqb, wkb, wvb (16384 elems each)

// ---------------- K0: cast weights to bf16 (natural [o][c] layout) ----------------
__global__ __launch_bounds__(256) void k_prep(const float* __restrict__ w0,
    const float* __restrict__ wq, const float* __restrict__ wk,
    const float* __restrict__ wv, ushort_t* __restrict__ wb) {
  int idx = blockIdx.x * 256 + threadIdx.x;  // 0..65535
  int m = idx >> 14;
  int e = idx & 16383;
  const float* src = (m == 0) ? w0 : (m == 1) ? wq : (m == 2) ? wk : wv;
  wb[m * 16384 + e] = f2bf(src[e]);
}

// ---- cooperative staging: Xt[col][cin] bf16 into LDS (transposed, padded) ----
__device__ __forceinline__ void stage_xt(const float* __restrict__ xb,
                                         ushort_t* __restrict__ xt, int tid) {
  const int col = tid & 127;
  const int hi = tid >> 7;  // 0/1: which half of the cin chunks
  const float* p = xb + col;
#pragma unroll
  for (int i = 0; i < 8; ++i) {
    const int c0 = hi * 64 + i * 8;
    ushort_t u[8] __attribute__((aligned(16)));
#pragma unroll
    for (int j = 0; j < 8; ++j) u[j] = f2bf(p[(size_t)(c0 + j) * NK]);
    *(uint4*)(xt + col * XSTRIDE + c0) = *(const uint4*)u;
  }
}

// ---------------- K1: conv stats (sum, sumsq of conv output, no bias) ----------------
// Wave owns a 16-output-channel strip per pass; w0 fragments live in registers.
// D[row=col-in-tile][colD=outch]: A = Xt rows (positions), B = w0 strip rows.
__global__ __launch_bounds__(256, 4) void k_stats(const float* __restrict__ x,
    const ushort_t* __restrict__ w0b, float* __restrict__ sum,
    float* __restrict__ sq) {
  __shared__ ushort_t xt[128 * XSTRIDE];
  const int b = blockIdx.y;
  const int col0 = blockIdx.x * 128;
  const int tid = threadIdx.x;
  stage_xt(x + (size_t)b * NC * NK + col0, xt, tid);
  __syncthreads();
  const int lane = tid & 63, w = tid >> 6;
  const int m = lane & 15, quad = lane >> 4;

#pragma unroll 1
  for (int p = 0; p < 2; ++p) {
    const int ch0 = (w + p * 4) * 16;  // this wave's output-channel strip
    bf16x8 wf[4];
#pragma unroll
    for (int kb = 0; kb < 4; ++kb)
      wf[kb] = *(const bf16x8*)(w0b + (ch0 + m) * 128 + kb * 32 + quad * 8);
    float s = 0.f, q2 = 0.f;
#pragma unroll 2
    for (int t = 0; t < 8; ++t) {
      const ushort_t* xr = xt + (t * 16 + m) * XSTRIDE;
      f32x4 acc = {0.f, 0.f, 0.f, 0.f};
#pragma unroll
      for (int kb = 0; kb < 4; ++kb) {
        bf16x8 af = *(const bf16x8*)(xr + kb * 32 + quad * 8);
        acc = mfma_bf16(af, wf[kb], acc);
      }
      s += (acc[0] + acc[1]) + (acc[2] + acc[3]);
      q2 += (acc[0] * acc[0] + acc[1] * acc[1]) +
            (acc[2] * acc[2] + acc[3] * acc[3]);
    }
    // rows (positions) live across quads: reduce, then atomic per channel
    s += __shfl_xor(s, 16);
    s += __shfl_xor(s, 32);
    q2 += __shfl_xor(q2, 16);
    q2 += __shfl_xor(q2, 32);
    if (quad == 0) {
      atomicAdd(&sum[b * 128 + ch0 + m], s);
      atomicAdd(&sq[b * 128 + ch0 + m], q2);
    }
  }
}

// ---------------- K2: fold IN+BN into per-(b,c) alpha/beta ----------------
// conv bias b0 cancels inside IN. BN mean == 0 exactly (IN zero-means each (b,c)).
__global__ void k_fold(const float* __restrict__ ws_in, const float* __restrict__ bn_g,
                       const float* __restrict__ bn_b, float* __restrict__ alpha,
                       float* __restrict__ beta) {
  int c = threadIdx.x;  // 128 threads
  const float* sum = ws_in;
  const float* sq = ws_in + 1024;
  float var[NB], muv[NB];
  float bvar = 0.f;
#pragma unroll
  for (int b = 0; b < NB; ++b) {
    float mu = sum[b * 128 + c] * (1.f / NK);
    float v = sq[b * 128 + c] * (1.f / NK) - mu * mu;
    muv[b] = mu;
    var[b] = v;
    bvar += v / (v + IN_EPS);
  }
  bvar *= 0.125f;
  float s2 = rsqrtf(bvar + BN_EPS);
  float g = bn_g[c], bb = bn_b[c];
#pragma unroll
  for (int b = 0; b < NB; ++b) {
    float a = rsqrtf(var[b] + IN_EPS) * s2 * g;
    alpha[b * 128 + c] = a;
    beta[b * 128 + c] = bb - muv[b] * a;
  }
}

// ---------------- K3: fused conv+norm+qkv+softmax+agg ----------------
// Wave owns 16-out-ch strips (passes p=0,1 -> strips w, w+4); weight fragments
// register-resident per pass. H results held packed in registers across a
// barrier, then written in place over Xt (becomes Ht). QKV reads only LDS.
__global__ __launch_bounds__(256, 4) void k_fused(const float* __restrict__ x,
    const float* __restrict__ x_row, const ushort_t* __restrict__ wb,
    const float* __restrict__ alpha, const float* __restrict__ beta,
    const float* __restrict__ bq, const float* __restrict__ bk,
    const float* __restrict__ bv, const float* __restrict__ g1p,
    float* __restrict__ out) {
  __shared__ ushort_t xt[128 * XSTRIDE];  // 34816 B
  __shared__ float souts[128 * 8];        // 4096 B -> total 38912 B (4 blocks/CU)
  const int b = blockIdx.y;
  const int tid = threadIdx.x;
  stage_xt(x + (size_t)b * NC * NK + (size_t)blockIdx.x * 128, xt, tid);
  __syncthreads();
  const int lane = tid & 63, w = tid >> 6;
  const int m = lane & 15, quad = lane >> 4;
  const ushort_t* w0b = wb;
  const ushort_t* wqb = wb + 16384;
  const ushort_t* wkb = wb + 32768;
  const ushort_t* wvb = wb + 49152;

  // ---------------- H phase: compute both strips into registers ----------------
  uint2 hpk[2][8];
#pragma unroll
  for (int p = 0; p < 2; ++p) {
    const int ch0 = (w + p * 4) * 16;
    bf16x8 wf[4];
#pragma unroll
    for (int kb = 0; kb < 4; ++kb)
      wf[kb] = *(const bf16x8*)(w0b + (ch0 + m) * 128 + kb * 32 + quad * 8);
    const float4 av = *(const float4*)(alpha + b * 128 + ch0 + quad * 4);
    const float4 bev = *(const float4*)(beta + b * 128 + ch0 + quad * 4);
#pragma unroll
    for (int t = 0; t < 8; ++t) {
      const ushort_t* xr = xt + (t * 16 + m) * XSTRIDE;
      f32x4 acc = {0.f, 0.f, 0.f, 0.f};
#pragma unroll
      for (int kb = 0; kb < 4; ++kb) {
        bf16x8 bx = *(const bf16x8*)(xr + kb * 32 + quad * 8);
        acc = mfma_bf16(wf[kb], bx, acc);
      }
      // D: col=lane&15 -> col-in-tile, row=quad*4+r -> ch-in-strip
      float h0 = fmaxf(acc[0] * av.x + bev.x, 0.f);
      float h1 = fmaxf(acc[1] * av.y + bev.y, 0.f);
      float h2 = fmaxf(acc[2] * av.z + bev.z, 0.f);
      float h3 = fmaxf(acc[3] * av.w + bev.w, 0.f);
      uint2 pk;
      pk.x = (unsigned)f2bf(h0) | ((unsigned)f2bf(h1) << 16);
      pk.y = (unsigned)f2bf(h2) | ((unsigned)f2bf(h3) << 16);
      hpk[p][t] = pk;
    }
  }
  __syncthreads();  // all Xt reads complete before overwrite
#pragma unroll
  for (int p = 0; p < 2; ++p)
#pragma unroll
    for (int t = 0; t < 8; ++t)
      *(uint2*)(xt + (t * 16 + m) * XSTRIDE + (w + p * 4) * 16 + quad * 4) =
          hpk[p][t];
  __syncthreads();  // Ht complete

  // ---------------- QKV phase ----------------
#pragma unroll 1
  for (int p = 0; p < 2; ++p) {
    const int ch0 = (w + p * 4) * 16;
    bf16x8 wqf[4], wkf[4], wvf[4];
#pragma unroll
    for (int kb = 0; kb < 4; ++kb) {
      wqf[kb] = *(const bf16x8*)(wqb + (ch0 + m) * 128 + kb * 32 + quad * 8);
      wkf[kb] = *(const bf16x8*)(wkb + (ch0 + m) * 128 + kb * 32 + quad * 8);
      wvf[kb] = *(const bf16x8*)(wvb + (ch0 + m) * 128 + kb * 32 + quad * 8);
    }
    const float bqv = bq[ch0 + m];
    const float bkv = bk[ch0 + m];
    const float bvv = bv[ch0 + m];
#pragma unroll 1
    for (int t = 0; t < 8; ++t) {
      const ushort_t* hr = xt + (t * 16 + m) * XSTRIDE;
      bf16x8 af[4];
#pragma unroll
      for (int kb = 0; kb < 4; ++kb)
        af[kb] = *(const bf16x8*)(hr + kb * 32 + quad * 8);
      f32x4 qa = {0.f, 0.f, 0.f, 0.f};
      f32x4 ka = {0.f, 0.f, 0.f, 0.f};
#pragma unroll
      for (int kb = 0; kb < 4; ++kb) qa = mfma_bf16(af[kb], wqf[kb], qa);
#pragma unroll
      for (int kb = 0; kb < 4; ++kb) ka = mfma_bf16(af[kb], wkf[kb], ka);
      // D: col=lane&15 -> outch-in-strip, row=quad*4+r -> neighbor
      float p0 = (qa[0] + bqv) * (ka[0] + bkv);
      float p1 = (qa[1] + bqv) * (ka[1] + bkv);
      float p2 = (qa[2] + bqv) * (ka[2] + bkv);
      float p3 = (qa[3] + bqv) * (ka[3] + bkv);
      float mx = fmaxf(fmaxf(p0, p1), fmaxf(p2, p3));
      mx = fmaxf(mx, __shfl_xor(mx, 16));
      mx = fmaxf(mx, __shfl_xor(mx, 32));
      float e0 = __expf(p0 - mx), e1 = __expf(p1 - mx);
      float e2 = __expf(p2 - mx), e3 = __expf(p3 - mx);
      float sm = (e0 + e1) + (e2 + e3);
      sm += __shfl_xor(sm, 16);
      sm += __shfl_xor(sm, 32);
      f32x4 va = {0.f, 0.f, 0.f, 0.f};
#pragma unroll
      for (int kb = 0; kb < 4; ++kb) va = mfma_bf16(af[kb], wvf[kb], va);
      float r0 = e0 * (va[0] + bvv) + e1 * (va[1] + bvv) +
                 e2 * (va[2] + bvv) + e3 * (va[3] + bvv);
      r0 += __shfl_xor(r0, 16);
      r0 += __shfl_xor(r0, 32);
      if (quad == 0) souts[(ch0 + m) * 8 + t] = r0 / sm;
    }
  }
  __syncthreads();

  // ---- coalesced epilogue: out = x_row + g1 * souts ----
  {
    const float g1 = g1p[0];
    const int c = tid >> 1, half = tid & 1;
    const int n0 = blockIdx.x * 8 + half * 4;
    const size_t oi = ((size_t)b * NC + c) * NPOS + n0;
    const float4 xr = *(const float4*)(x_row + oi);
    const float* sp = souts + c * 8 + half * 4;
    float4 o;
    o.x = xr.x + g1 * sp[0];
    o.y = xr.y + g1 * sp[1];
    o.z = xr.z + g1 * sp[2];
    o.w = xr.w + g1 * sp[3];
    *(float4*)(out + oi) = o;
  }
}

extern "C" void kernel_launch(void* const* d_in, const int* in_sizes, int n_in,
                              void* d_out, int out_size, void* d_ws, size_t ws_size,
                              hipStream_t stream) {
  (void)in_sizes; (void)n_in; (void)out_size; (void)ws_size;
  const float* x_row   = (const float*)d_in[0];
  const float* x_local = (const float*)d_in[1];
  const float* w0   = (const float*)d_in[2];
  const float* bn_g = (const float*)d_in[4];
  const float* bn_b = (const float*)d_in[5];
  const float* wq   = (const float*)d_in[6];
  const float* bq   = (const float*)d_in[7];
  const float* wk   = (const float*)d_in[8];
  const float* bk   = (const float*)d_in[9];
  const float* wv   = (const float*)d_in[10];
  const float* bv   = (const float*)d_in[11];
  const float* gamma1 = (const float*)d_in[12];
  float* out = (float*)d_out;
  float* ws = (float*)d_ws;
  ushort_t* wb = (ushort_t*)((char*)d_ws + 16384);

  hipMemsetAsync(ws, 0, 2048 * sizeof(float), stream);  // sum/sumsq accumulators
  k_prep<<<256, 256, 0, stream>>>(w0, wq, wk, wv, wb);
  k_stats<<<dim3(250, NB), 256, 0, stream>>>(x_local, wb, ws, ws + 1024);
  k_fold<<<1, 128, 0, stream>>>(ws, bn_g, bn_b, ws + 2048, ws + 3072);
  k_fused<<<dim3(250, NB), 256, 0, stream>>>(x_local, x_row, wb, ws + 2048,
                                             ws + 3072, bq, bk, bv, gamma1, out);
}

// Round 6
// 310.886 us; speedup vs baseline: 2.8288x; 1.0216x over previous
//
#include <hip/hip_runtime.h>
#include <math.h>

#define NB 8
#define NC 128
#define NPOS 2000
#define NK 32000
#define IN_EPS 1e-3f
#define BN_EPS 1e-5f

typedef short bf16x8 __attribute__((ext_vector_type(8)));
typedef float f32x4 __attribute__((ext_vector_type(4)));
typedef unsigned short ushort_t;

// LDS row stride in ushorts (128 payload + 8 pad; keeps 16B alignment)
#define XSTRIDE 136

// ---- workspace layout (float offsets) ----
// [0 .. 32768)      sumP  : 32 buckets x (8b x 128c), bucket-major
// [32768 .. 65536)  sqP
// [65536 .. 66560)  alpha
// [66560 .. 67584)  beta
// byte 270336:      bf16 weights w0b,wqb,wkb,wvb (16384 ushorts each)
#define WSF_SUMP  0
#define WSF_SQP   32768
#define WSF_ALPHA 65536
#define WSF_BETA  66560
#define WSB_WEIGHTS 270336

__device__ __forceinline__ f32x4 mfma_bf16(bf16x8 a, bf16x8 b, f32x4 c) {
  return __builtin_amdgcn_mfma_f32_16x16x32_bf16(a, b, c, 0, 0, 0);
}

// fp32 -> bf16 round-to-nearest-even
__device__ __forceinline__ ushort_t f2bf(float f) {
  unsigned u = __float_as_uint(f);
  return (ushort_t)((u + 0x7FFFu + ((u >> 16) & 1u)) >> 16);
}

// ---------------- K0: cast weights to bf16 (natural [o][c] layout) ----------------
__global__ __launch_bounds__(256) void k_prep(const float* __restrict__ w0,
    const float* __restrict__ wq, const float* __restrict__ wk,
    const float* __restrict__ wv, ushort_t* __restrict__ wb) {
  int idx = blockIdx.x * 256 + threadIdx.x;  // 0..65535
  int m = idx >> 14;
  int e = idx & 16383;
  const float* src = (m == 0) ? w0 : (m == 1) ? wq : (m == 2) ? wk : wv;
  wb[m * 16384 + e] = f2bf(src[e]);
}

// ---- staging: Xt[col][cin] bf16 into LDS, 128 columns ----
__device__ __forceinline__ void stage_xt128(const float* __restrict__ xb,
                                            ushort_t* __restrict__ xt, int tid) {
  const int col = tid & 127;
  const int hi = tid >> 7;  // 0/1
  const float* p = xb + col;
#pragma unroll
  for (int i = 0; i < 8; ++i) {
    const int c0 = hi * 64 + i * 8;
    ushort_t u[8] __attribute__((aligned(16)));
#pragma unroll
    for (int j = 0; j < 8; ++j) u[j] = f2bf(p[(size_t)(c0 + j) * NK]);
    *(uint4*)(xt + col * XSTRIDE + c0) = *(const uint4*)u;
  }
}

// ---- staging: 64 columns ----
__device__ __forceinline__ void stage_xt64(const float* __restrict__ xb,
                                           ushort_t* __restrict__ xt, int tid) {
  const int col = tid & 63;
  const int hi = tid >> 6;  // 0..3
  const float* p = xb + col;
#pragma unroll
  for (int i = 0; i < 4; ++i) {
    const int c0 = hi * 32 + i * 8;
    ushort_t u[8] __attribute__((aligned(16)));
#pragma unroll
    for (int j = 0; j < 8; ++j) u[j] = f2bf(p[(size_t)(c0 + j) * NK]);
    *(uint4*)(xt + col * XSTRIDE + c0) = *(const uint4*)u;
  }
}

// ---------------- K1: conv stats (sum, sumsq of conv output, no bias) ----------------
// Wave owns a 16-output-channel strip per pass; w0 fragments register-resident.
// Partials to LDS (strips disjoint -> plain stores), then one coalesced
// atomicAdd per channel into a 32-way bucketed global accumulator.
__global__ __launch_bounds__(256, 4) void k_stats(const float* __restrict__ x,
    const ushort_t* __restrict__ w0b, float* __restrict__ sumP,
    float* __restrict__ sqP) {
  __shared__ ushort_t xt[128 * XSTRIDE];
  __shared__ float ssum[128], ssq[128];
  const int b = blockIdx.y;
  const int tid = threadIdx.x;
  stage_xt128(x + (size_t)b * NC * NK + (size_t)blockIdx.x * 128, xt, tid);
  __syncthreads();
  const int lane = tid & 63, w = tid >> 6;
  const int m = lane & 15, quad = lane >> 4;

#pragma unroll 1
  for (int p = 0; p < 2; ++p) {
    const int ch0 = (w + p * 4) * 16;  // this wave's output-channel strip
    bf16x8 wf[4];
#pragma unroll
    for (int kb = 0; kb < 4; ++kb)
      wf[kb] = *(const bf16x8*)(w0b + (ch0 + m) * 128 + kb * 32 + quad * 8);
    float s = 0.f, q2 = 0.f;
#pragma unroll 2
    for (int t = 0; t < 8; ++t) {
      const ushort_t* xr = xt + (t * 16 + m) * XSTRIDE;
      f32x4 acc = {0.f, 0.f, 0.f, 0.f};
#pragma unroll
      for (int kb = 0; kb < 4; ++kb) {
        bf16x8 af = *(const bf16x8*)(xr + kb * 32 + quad * 8);
        acc = mfma_bf16(af, wf[kb], acc);
      }
      s += (acc[0] + acc[1]) + (acc[2] + acc[3]);
      q2 += (acc[0] * acc[0] + acc[1] * acc[1]) +
            (acc[2] * acc[2] + acc[3] * acc[3]);
    }
    // positions live across quads: reduce, then plain store (strips disjoint)
    s += __shfl_xor(s, 16);
    s += __shfl_xor(s, 32);
    q2 += __shfl_xor(q2, 16);
    q2 += __shfl_xor(q2, 32);
    if (quad == 0) {
      ssum[ch0 + m] = s;
      ssq[ch0 + m] = q2;
    }
  }
  __syncthreads();
  if (tid < 128) {
    const int bucket = blockIdx.x & 31;
    atomicAdd(&sumP[bucket * 1024 + b * 128 + tid], ssum[tid]);
    atomicAdd(&sqP[bucket * 1024 + b * 128 + tid], ssq[tid]);
  }
}

// ---------------- K2: reduce buckets, fold IN+BN into per-(b,c) alpha/beta ----------------
// conv bias b0 cancels inside IN. BN mean == 0 exactly (IN zero-means each (b,c)).
__global__ void k_fold(const float* __restrict__ ws_in, const float* __restrict__ bn_g,
                       const float* __restrict__ bn_b, float* __restrict__ alpha,
                       float* __restrict__ beta) {
  int c = threadIdx.x;  // 128 threads
  const float* sumP = ws_in + WSF_SUMP;
  const float* sqP = ws_in + WSF_SQP;
  float var[NB], muv[NB];
  float bvar = 0.f;
#pragma unroll 1
  for (int b = 0; b < NB; ++b) {
    float s = 0.f, q = 0.f;
#pragma unroll
    for (int k = 0; k < 32; ++k) {
      s += sumP[k * 1024 + b * 128 + c];
      q += sqP[k * 1024 + b * 128 + c];
    }
    float mu = s * (1.f / NK);
    float v = q * (1.f / NK) - mu * mu;
    muv[b] = mu;
    var[b] = v;
    bvar += v / (v + IN_EPS);
  }
  bvar *= 0.125f;
  float s2 = rsqrtf(bvar + BN_EPS);
  float g = bn_g[c], bb = bn_b[c];
#pragma unroll
  for (int b = 0; b < NB; ++b) {
    float a = rsqrtf(var[b] + IN_EPS) * s2 * g;
    alpha[b * 128 + c] = a;
    beta[b * 128 + c] = bb - muv[b] * a;
  }
}

// ---------------- K3: fused conv+norm+qkv+softmax+agg ----------------
// 64-position tile. H streams straight into a separate Ht LDS buffer -> zero
// cross-barrier register state (no spills). One barrier between H and QKV.
__global__ __launch_bounds__(256, 4) void k_fused(const float* __restrict__ x,
    const float* __restrict__ x_row, const ushort_t* __restrict__ wb,
    const float* __restrict__ alpha, const float* __restrict__ beta,
    const float* __restrict__ bq, const float* __restrict__ bk,
    const float* __restrict__ bv, const float* __restrict__ g1p,
    float* __restrict__ out) {
  __shared__ ushort_t xt[64 * XSTRIDE];  // 17408 B
  __shared__ ushort_t ht[64 * XSTRIDE];  // 17408 B
  __shared__ float souts[128 * 5];       // 2560 B  -> 37376 B total, 4 blocks/CU
  const int b = blockIdx.y;
  const int tid = threadIdx.x;
  stage_xt64(x + (size_t)b * NC * NK + (size_t)blockIdx.x * 64, xt, tid);
  const float g1 = g1p[0];
  __syncthreads();
  const int lane = tid & 63, w = tid >> 6;
  const int m = lane & 15, quad = lane >> 4;
  const ushort_t* w0b = wb;
  const ushort_t* wqb = wb + 16384;
  const ushort_t* wkb = wb + 32768;
  const ushort_t* wvb = wb + 49152;

  // ---------------- H phase: stream normalized H into ht ----------------
#pragma unroll 1
  for (int p = 0; p < 2; ++p) {
    const int ch0 = (w + p * 4) * 16;
    bf16x8 wf[4];
#pragma unroll
    for (int kb = 0; kb < 4; ++kb)
      wf[kb] = *(const bf16x8*)(w0b + (ch0 + m) * 128 + kb * 32 + quad * 8);
    const float4 av = *(const float4*)(alpha + b * 128 + ch0 + quad * 4);
    const float4 bev = *(const float4*)(beta + b * 128 + ch0 + quad * 4);
#pragma unroll
    for (int t = 0; t < 4; ++t) {
      const ushort_t* xr = xt + (t * 16 + m) * XSTRIDE;
      f32x4 acc = {0.f, 0.f, 0.f, 0.f};
#pragma unroll
      for (int kb = 0; kb < 4; ++kb) {
        bf16x8 bx = *(const bf16x8*)(xr + kb * 32 + quad * 8);
        acc = mfma_bf16(wf[kb], bx, acc);
      }
      // D: col=lane&15 -> position, row=quad*4+r -> ch-in-strip
      float h0 = fmaxf(acc[0] * av.x + bev.x, 0.f);
      float h1 = fmaxf(acc[1] * av.y + bev.y, 0.f);
      float h2 = fmaxf(acc[2] * av.z + bev.z, 0.f);
      float h3 = fmaxf(acc[3] * av.w + bev.w, 0.f);
      uint2 pk;
      pk.x = (unsigned)f2bf(h0) | ((unsigned)f2bf(h1) << 16);
      pk.y = (unsigned)f2bf(h2) | ((unsigned)f2bf(h3) << 16);
      *(uint2*)(ht + (t * 16 + m) * XSTRIDE + ch0 + quad * 4) = pk;
    }
  }
  __syncthreads();  // Ht complete

  // ---------------- QKV phase ----------------
#pragma unroll 1
  for (int p = 0; p < 2; ++p) {
    const int ch0 = (w + p * 4) * 16;
    bf16x8 wqf[4], wkf[4], wvf[4];
#pragma unroll
    for (int kb = 0; kb < 4; ++kb) {
      wqf[kb] = *(const bf16x8*)(wqb + (ch0 + m) * 128 + kb * 32 + quad * 8);
      wkf[kb] = *(const bf16x8*)(wkb + (ch0 + m) * 128 + kb * 32 + quad * 8);
      wvf[kb] = *(const bf16x8*)(wvb + (ch0 + m) * 128 + kb * 32 + quad * 8);
    }
    const float bqv = bq[ch0 + m];
    const float bkv = bk[ch0 + m];
    const float bvv = bv[ch0 + m];
#pragma unroll 1
    for (int t = 0; t < 4; ++t) {
      const ushort_t* hr = ht + (t * 16 + m) * XSTRIDE;
      bf16x8 af[4];
#pragma unroll
      for (int kb = 0; kb < 4; ++kb)
        af[kb] = *(const bf16x8*)(hr + kb * 32 + quad * 8);
      f32x4 qa = {0.f, 0.f, 0.f, 0.f};
      f32x4 ka = {0.f, 0.f, 0.f, 0.f};
#pragma unroll
      for (int kb = 0; kb < 4; ++kb) qa = mfma_bf16(af[kb], wqf[kb], qa);
#pragma unroll
      for (int kb = 0; kb < 4; ++kb) ka = mfma_bf16(af[kb], wkf[kb], ka);
      // D: col=lane&15 -> outch-in-strip, row=quad*4+r -> neighbor
      float p0 = (qa[0] + bqv) * (ka[0] + bkv);
      float p1 = (qa[1] + bqv) * (ka[1] + bkv);
      float p2 = (qa[2] + bqv) * (ka[2] + bkv);
      float p3 = (qa[3] + bqv) * (ka[3] + bkv);
      float mx = fmaxf(fmaxf(p0, p1), fmaxf(p2, p3));
      mx = fmaxf(mx, __shfl_xor(mx, 16));
      mx = fmaxf(mx, __shfl_xor(mx, 32));
      float e0 = __expf(p0 - mx), e1 = __expf(p1 - mx);
      float e2 = __expf(p2 - mx), e3 = __expf(p3 - mx);
      float sm = (e0 + e1) + (e2 + e3);
      sm += __shfl_xor(sm, 16);
      sm += __shfl_xor(sm, 32);
      f32x4 va = {0.f, 0.f, 0.f, 0.f};
#pragma unroll
      for (int kb = 0; kb < 4; ++kb) va = mfma_bf16(af[kb], wvf[kb], va);
      float r0 = e0 * (va[0] + bvv) + e1 * (va[1] + bvv) +
                 e2 * (va[2] + bvv) + e3 * (va[3] + bvv);
      r0 += __shfl_xor(r0, 16);
      r0 += __shfl_xor(r0, 32);
      if (quad == 0) souts[(ch0 + m) * 5 + t] = r0 / sm;
    }
  }
  __syncthreads();

  // ---- coalesced epilogue: out = x_row + g1 * souts ----
  if (tid < 128) {
    const int c = tid;
    const size_t oi = ((size_t)b * NC + c) * NPOS + blockIdx.x * 4;
    const float4 xr = *(const float4*)(x_row + oi);
    const float* sp = souts + c * 5;
    float4 o;
    o.x = xr.x + g1 * sp[0];
    o.y = xr.y + g1 * sp[1];
    o.z = xr.z + g1 * sp[2];
    o.w = xr.w + g1 * sp[3];
    *(float4*)(out + oi) = o;
  }
}

extern "C" void kernel_launch(void* const* d_in, const int* in_sizes, int n_in,
                              void* d_out, int out_size, void* d_ws, size_t ws_size,
                              hipStream_t stream) {
  (void)in_sizes; (void)n_in; (void)out_size; (void)ws_size;
  const float* x_row   = (const float*)d_in[0];
  const float* x_local = (const float*)d_in[1];
  const float* w0   = (const float*)d_in[2];
  const float* bn_g = (const float*)d_in[4];
  const float* bn_b = (const float*)d_in[5];
  const float* wq   = (const float*)d_in[6];
  const float* bq   = (const float*)d_in[7];
  const float* wk   = (const float*)d_in[8];
  const float* bk   = (const float*)d_in[9];
  const float* wv   = (const float*)d_in[10];
  const float* bv   = (const float*)d_in[11];
  const float* gamma1 = (const float*)d_in[12];
  float* out = (float*)d_out;
  float* ws = (float*)d_ws;
  ushort_t* wb = (ushort_t*)((char*)d_ws + WSB_WEIGHTS);

  hipMemsetAsync(ws, 0, 65536 * sizeof(float), stream);  // bucketed accumulators
  k_prep<<<256, 256, 0, stream>>>(w0, wq, wk, wv, wb);
  k_stats<<<dim3(250, NB), 256, 0, stream>>>(x_local, wb, ws + WSF_SUMP,
                                             ws + WSF_SQP);
  k_fold<<<1, 128, 0, stream>>>(ws, bn_g, bn_b, ws + WSF_ALPHA, ws + WSF_BETA);
  k_fused<<<dim3(500, NB), 256, 0, stream>>>(x_local, x_row, wb, ws + WSF_ALPHA,
                                             ws + WSF_BETA, bq, bk, bv, gamma1,
                                             out);
}